// Round 26
// baseline (145.139 us; speedup 1.0000x reference)
//
#include <hip/hip_runtime.h>
#include <hip/hip_fp16.h>

#define N_NODES 100000
#define N_EDGES 1600000
#define IN_DIM  256
#define OUT_DIM 128

#define BROWS  256                     // rows per bucket
#define NBKT   391                     // ceil(100000/256)
#define CAP    4608                    // per-bucket capacity (mean 4096 + 8 sigma)
#define CHUNK  2048                    // edges per bin block (standalone: 782 blocks)
#define NBLK   782                     // ceil(1600000/2048)
#define DCAP   6144                    // LDS sort capacity
#define BSTR   16                      // bcnt stride (ints): 1 counter per 64B line

#define BMT    32                      // pipelined gemm tile rows (16 KB bf16 LDS)
#define NTILE  (N_NODES / BMT)         // 3125 (exact)
#define TPB    4                       // tiles per gemm block
#define NGBLK  ((NTILE + TPB - 1) / TPB)   // 782
#define BUFSZ  (BMT * 512)

typedef __attribute__((ext_vector_type(8))) short short8;
typedef __attribute__((ext_vector_type(4))) float f32x4;
typedef __attribute__((ext_vector_type(2))) float f32x2;

// f32 -> bf16 round-to-nearest-even (bit trick)
__device__ __forceinline__ unsigned short f2bf(float f) {
    unsigned int u = __float_as_uint(f);
    u += 0x7FFFu + ((u >> 16) & 1u);
    return (unsigned short)(u >> 16);
}
__device__ __forceinline__ float bf2f(unsigned int u16) {
    return __uint_as_float(u16 << 16);
}

__device__ __forceinline__ short8 pack8(float4 a, float4 b) {
    short8 s;
    s[0] = (short)f2bf(a.x); s[1] = (short)f2bf(a.y);
    s[2] = (short)f2bf(a.z); s[3] = (short)f2bf(a.w);
    s[4] = (short)f2bf(b.x); s[5] = (short)f2bf(b.y);
    s[6] = (short)f2bf(b.z); s[7] = (short)f2bf(b.w);
    return s;
}

// ---------------------------------------------------------------------------
// W (f32 [128][256]) -> bf16, once; block 0 also zeros padded bcnt.
// ---------------------------------------------------------------------------
__global__ __launch_bounds__(256) void w_to_bf16(const float* __restrict__ W,
                                                 unsigned short* __restrict__ Wb,
                                                 int* __restrict__ bcnt) {
    int i = blockIdx.x * 256 + threadIdx.x;
    if (i < OUT_DIM * IN_DIM) Wb[i] = f2bf(W[i]);
    if (blockIdx.x == 0) {
        for (int b = threadIdx.x; b < NBKT * BSTR; b += 256) bcnt[b] = 0;
    }
}

// ---------------------------------------------------------------------------
// Standalone bin pass (782 blocks x 2048 edges, 256 thr -> high TLP):
// LDS histogram -> line-padded reservation -> record placement.
// rec = fp16(val)<<17 | col.
// ---------------------------------------------------------------------------
__global__ __launch_bounds__(256) void bin_pass(const int* __restrict__ erow,
                                                const int* __restrict__ ecol,
                                                const float* __restrict__ eval,
                                                int* __restrict__ bcnt,
                                                int2* __restrict__ gbuf) {
    __shared__ int h[NBKT], gpos[NBKT], rcur[NBKT];
    const int tid = threadIdx.x;
    for (int i = tid; i < NBKT; i += 256) { h[i] = 0; rcur[i] = 0; }
    __syncthreads();
    const int e0 = blockIdx.x * CHUNK;
    for (int i = tid; i < CHUNK; i += 256) {
        int e = e0 + i;
        if (e < N_EDGES) atomicAdd(&h[erow[e] >> 8], 1);
    }
    __syncthreads();
    for (int i = tid; i < NBKT; i += 256)
        gpos[i] = h[i] ? (i * CAP + atomicAdd(&bcnt[i * BSTR], h[i])) : 0;
    __syncthreads();
    for (int i = tid; i < CHUNK; i += 256) {
        int e = e0 + i;
        if (e < N_EDGES) {
            int r = erow[e];
            int b = r >> 8;
            unsigned int vb  = __half_as_ushort(__float2half(eval[e]));
            unsigned int rec = (vb << 17) | (unsigned int)ecol[e];
            int pos = gpos[b] + atomicAdd(&rcur[b], 1);
            gbuf[pos] = make_int2((int)rec, r);
        }
    }
}

// ---------------------------------------------------------------------------
// Standalone GEMM (R24-proven body): 4-tile pipelined, 782 blocks.
// ---------------------------------------------------------------------------
__global__ __launch_bounds__(512) void gemm_mfma(const float* __restrict__ x,
                                                 const unsigned short* __restrict__ Wb,
                                                 unsigned short* __restrict__ hb) {
    __shared__ unsigned short xs[2 * BMT * 256];   // 32 KB
    const int tid  = threadIdx.x;
    const int t0   = blockIdx.x * TPB;
    const int wid  = tid >> 6;
    const int lane = tid & 63;
    const int l15  = lane & 15;
    const int g8   = (lane >> 4) * 8;
    const int col  = wid * 16 + l15;
    const int sw   = (l15 & 7) << 4;
    char* lb = (char*)xs;

    const int srow = tid >> 4;
    const int ca   = (tid & 15) * 8;
    const int swr  = (srow & 7) << 4;
    const int wbA  = (srow * 512 + ca * 2) ^ swr;
    const int wbB  = (srow * 512 + (ca + 128) * 2) ^ swr;

    short8 bfr[8];
    const unsigned short* wrow = Wb + (size_t)col * IN_DIM + g8;
#pragma unroll
    for (int kk = 0; kk < 8; ++kk)
        bfr[kk] = *(const short8*)(wrow + kk * 32);

    // prologue: load + write tile t0 into buffer 0
    {
        const int ti = t0;
        const int gr = (ti < NTILE) ? (ti * BMT + srow) : srow;
        const float4* sA = (const float4*)(x + (size_t)gr * IN_DIM + ca);
        const float4* sB = (const float4*)(x + (size_t)gr * IN_DIM + ca + 128);
        float4 f0 = sA[0], f1 = sA[1], f2 = sB[0], f3 = sB[1];
        *(short8*)(lb + wbA) = pack8(f0, f1);
        *(short8*)(lb + wbB) = pack8(f2, f3);
    }

#pragma unroll
    for (int i = 0; i < TPB; ++i) {
        float4 q0, q1, q2, q3;
        if (i + 1 < TPB) {
            const int ti = t0 + i + 1;
            const int gr = (ti < NTILE) ? (ti * BMT + srow) : srow;
            const float4* sA = (const float4*)(x + (size_t)gr * IN_DIM + ca);
            const float4* sB = (const float4*)(x + (size_t)gr * IN_DIM + ca + 128);
            q0 = sA[0]; q1 = sA[1]; q2 = sB[0]; q3 = sB[1];
        }
        __syncthreads();

        const int ti = t0 + i;
        const char* cb = lb + (i & 1) * BUFSZ;
        short8 a0[8], a1[8];
#pragma unroll
        for (int kk = 0; kk < 8; ++kk) {
            a0[kk] = *(const short8*)(cb + ((l15 * 512 + (kk * 32 + g8) * 2) ^ sw));
            a1[kk] = *(const short8*)(cb + (((l15 + 16) * 512 + (kk * 32 + g8) * 2) ^ sw));
        }
        f32x4 acc0 = {0.f, 0.f, 0.f, 0.f}, acc1 = {0.f, 0.f, 0.f, 0.f};
#pragma unroll
        for (int kk = 0; kk < 8; ++kk) {
            acc0 = __builtin_amdgcn_mfma_f32_16x16x32_bf16(a0[kk], bfr[kk], acc0, 0, 0, 0);
            acc1 = __builtin_amdgcn_mfma_f32_16x16x32_bf16(a1[kk], bfr[kk], acc1, 0, 0, 0);
        }
        if (ti < NTILE) {
            const int rb0 = ti * BMT + (lane >> 4) * 4;
            const int rb1 = rb0 + 16;
#pragma unroll
            for (int q = 0; q < 4; ++q) {
                hb[(size_t)(rb0 + q) * OUT_DIM + col] = f2bf(acc0[q]);
                hb[(size_t)(rb1 + q) * OUT_DIM + col] = f2bf(acc1[q]);
            }
        }
        if (i + 1 < TPB) {
            char* wbuf = lb + ((i + 1) & 1) * BUFSZ;
            *(short8*)(wbuf + wbA) = pack8(q0, q1);
            *(short8*)(wbuf + wbB) = pack8(q2, q3);
        }
    }
}

// ---------------------------------------------------------------------------
// Per-bucket LDS counting sort, 512 threads (R22-proven); cnt from padded bcnt.
// ---------------------------------------------------------------------------
__global__ __launch_bounds__(512) void sort_bucket(const int2* __restrict__ gbuf,
                                                   const int* __restrict__ bcnt,
                                                   unsigned int* __restrict__ gcsr,
                                                   int* __restrict__ offs,
                                                   int* __restrict__ bend) {
    __shared__ int rh[BROWS], rc[BROWS], tmp[256];
    __shared__ unsigned int lout[DCAP];
    const int b    = blockIdx.x;
    const int base = b * CAP;
    const int cnt  = bcnt[b * BSTR];
    const int r0   = b * BROWS;
    const int t    = threadIdx.x;

    if (t < BROWS) rh[t] = 0;
    __syncthreads();
    for (int i = t; i < cnt; i += 512)
        atomicAdd(&rh[gbuf[base + i].y - r0], 1);
    __syncthreads();

    int v = (t < 256) ? rh[t] : 0;
    if (t < 256) tmp[t] = v;
    __syncthreads();
    for (int d = 1; d < 256; d <<= 1) {
        int a = (t < 256 && t >= d) ? tmp[t - d] : 0;
        __syncthreads();
        if (t < 256) tmp[t] += a;
        __syncthreads();
    }
    if (t < 256) {
        int ex = tmp[t] - v;
        rc[t] = ex;
        offs[r0 + t] = base + ex;
    }
    if (t == 0) bend[b] = base + cnt;
    __syncthreads();

    if (cnt <= DCAP) {
        for (int i = t; i < cnt; i += 512) {
            int2 rr = gbuf[base + i];
            int p = atomicAdd(&rc[rr.y - r0], 1);
            lout[p] = (unsigned int)rr.x;
        }
        __syncthreads();
        for (int i = t; i < cnt; i += 512)
            gcsr[base + i] = lout[i];
    } else {  // unreachable (cnt <= CAP < DCAP); correctness fallback
        for (int i = t; i < cnt; i += 512) {
            int2 rr = gbuf[base + i];
            int p = atomicAdd(&rc[rr.y - r0], 1);
            gcsr[base + p] = (unsigned int)rr.x;
        }
    }
}

// ---------------------------------------------------------------------------
// Gather (R22-proven): 4 rows per wave, 8 channels/lane via uint4 loads.
// ---------------------------------------------------------------------------
__global__ __launch_bounds__(256) void spmm_gather(const unsigned short* __restrict__ hb,
                                                   const int* __restrict__ offs,
                                                   const int* __restrict__ bend,
                                                   const unsigned int* __restrict__ ccv,
                                                   float* __restrict__ out) {
    const int lane = threadIdx.x & 63;
    const int qtr  = lane >> 4;
    const int li   = lane & 15;
    const int r    = blockIdx.x * 16 + (threadIdx.x >> 6) * 4 + qtr;

    const int js = offs[r];
    const int je = ((r & (BROWS - 1)) == (BROWS - 1)) ? bend[r >> 8] : offs[r + 1];

    f32x2 acc0 = {0.f, 0.f}, acc1 = {0.f, 0.f};
    f32x2 acc2 = {0.f, 0.f}, acc3 = {0.f, 0.f};
    for (int j = js; __any(j < je); j += 8) {
        unsigned int e[8];
        uint4 p[8];
#pragma unroll
        for (int q = 0; q < 8; ++q) {
            int jj = j + q;
            e[q] = ccv[jj < je ? jj : 0];
        }
#pragma unroll
        for (int q = 0; q < 8; ++q)
            p[q] = *(const uint4*)(hb + (size_t)(e[q] & 0x1FFFFu) * OUT_DIM + li * 8);
#pragma unroll
        for (int q = 0; q < 8; ++q) {
            float v = (j + q < je)
                    ? __half2float(__ushort_as_half((unsigned short)(e[q] >> 17)))
                    : 0.f;
            f32x2 vv = {v, v};
            f32x2 h01 = { __uint_as_float(p[q].x << 16), __uint_as_float(p[q].x & 0xFFFF0000u) };
            f32x2 h23 = { __uint_as_float(p[q].y << 16), __uint_as_float(p[q].y & 0xFFFF0000u) };
            f32x2 h45 = { __uint_as_float(p[q].z << 16), __uint_as_float(p[q].z & 0xFFFF0000u) };
            f32x2 h67 = { __uint_as_float(p[q].w << 16), __uint_as_float(p[q].w & 0xFFFF0000u) };
            acc0 = __builtin_elementwise_fma(vv, h01, acc0);
            acc1 = __builtin_elementwise_fma(vv, h23, acc1);
            acc2 = __builtin_elementwise_fma(vv, h45, acc2);
            acc3 = __builtin_elementwise_fma(vv, h67, acc3);
        }
    }
    float4 o0 = {acc0.x, acc0.y, acc1.x, acc1.y};
    float4 o1 = {acc2.x, acc2.y, acc3.x, acc3.y};
    float* dst = out + (size_t)r * OUT_DIM + li * 8;
    *(float4*)dst       = o0;
    *(float4*)(dst + 4) = o1;
}

// ---------------------------------------------------------------------------
// Fallback path (workspace too small): plain gemm + atomic scatter.
// ---------------------------------------------------------------------------
__global__ __launch_bounds__(512) void gemm_plain(const float* __restrict__ x,
                                                  const float* __restrict__ W,
                                                  unsigned short* __restrict__ hb) {
    __shared__ unsigned short xs[2 * BMT * 256];
    const int tid = threadIdx.x;
    const int m0  = blockIdx.x * (2 * BMT);
    char* lb = (char*)xs;
    {
        const int row = tid >> 3;
        const int cs  = (tid & 7) * 32;
        const int gr  = m0 + row;
        if (gr < N_NODES) {
            const float4* src = (const float4*)(x + (size_t)gr * IN_DIM + cs);
#pragma unroll
            for (int i = 0; i < 4; ++i) {
                float4 a = src[2 * i], b = src[2 * i + 1];
                int byt = (row * 512 + (cs + 8 * i) * 2) ^ ((row & 7) << 4);
                *(short8*)(lb + byt) = pack8(a, b);
            }
        } else {
            short8 z = {0, 0, 0, 0, 0, 0, 0, 0};
#pragma unroll
            for (int i = 0; i < 4; ++i) {
                int byt = (row * 512 + (cs + 8 * i) * 2) ^ ((row & 7) << 4);
                *(short8*)(lb + byt) = z;
            }
        }
    }
    __syncthreads();
    const int wid  = tid >> 6;
    const int lane = tid & 63;
    const int l15  = lane & 15;
    const int g8   = (lane >> 4) * 8;
    short8 bfr[8];
    const float* wrowf = W + (size_t)(wid * 16 + l15) * IN_DIM + g8;
#pragma unroll
    for (int kk = 0; kk < 8; ++kk) {
        float4 wa = *(const float4*)(wrowf + kk * 32);
        float4 wb = *(const float4*)(wrowf + kk * 32 + 4);
        bfr[kk] = pack8(wa, wb);
    }
    const int col = wid * 16 + l15;
    const int sw  = (l15 & 7) << 4;
    const char* lbc = (const char*)xs;
#pragma unroll
    for (int rp = 0; rp < 2; ++rp) {
        const int r0 = rp * 32 + l15;
        const int r1 = r0 + 16;
        short8 a0[8], a1[8];
#pragma unroll
        for (int kk = 0; kk < 8; ++kk) {
            a0[kk] = *(const short8*)(lbc + ((r0 * 512 + (kk * 32 + g8) * 2) ^ sw));
            a1[kk] = *(const short8*)(lbc + ((r1 * 512 + (kk * 32 + g8) * 2) ^ sw));
        }
        f32x4 acc0 = {0.f, 0.f, 0.f, 0.f}, acc1 = {0.f, 0.f, 0.f, 0.f};
#pragma unroll
        for (int kk = 0; kk < 8; ++kk) {
            acc0 = __builtin_amdgcn_mfma_f32_16x16x32_bf16(a0[kk], bfr[kk], acc0, 0, 0, 0);
            acc1 = __builtin_amdgcn_mfma_f32_16x16x32_bf16(a1[kk], bfr[kk], acc1, 0, 0, 0);
        }
        const int rb0 = m0 + rp * 32 + (lane >> 4) * 4;
        const int rb1 = rb0 + 16;
#pragma unroll
        for (int i = 0; i < 4; ++i) {
            if (rb0 + i < N_NODES) hb[(size_t)(rb0 + i) * OUT_DIM + col] = f2bf(acc0[i]);
            if (rb1 + i < N_NODES) hb[(size_t)(rb1 + i) * OUT_DIM + col] = f2bf(acc1[i]);
        }
    }
}

__global__ __launch_bounds__(256) void spmm_scatter(const unsigned short* __restrict__ hb,
                                                    const int* __restrict__ erow,
                                                    const int* __restrict__ ecol,
                                                    const float* __restrict__ eval,
                                                    float* __restrict__ out) {
    const int lane = threadIdx.x & 63;
    const int eloc = threadIdx.x >> 6;
    const int stride = gridDim.x * 4;
    for (int e = blockIdx.x * 4 + eloc; e < N_EDGES; e += stride) {
        const int r = erow[e];
        const int c = ecol[e];
        const float v = eval[e];
        unsigned int p = *(const unsigned int*)(hb + (size_t)c * OUT_DIM + lane * 2);
        float* o = out + (size_t)r * OUT_DIM + lane * 2;
        unsafeAtomicAdd(o + 0, v * bf2f(p & 0xFFFFu));
        unsafeAtomicAdd(o + 1, v * bf2f(p >> 16));
    }
}

extern "C" void kernel_launch(void* const* d_in, const int* in_sizes, int n_in,
                              void* d_out, int out_size, void* d_ws, size_t ws_size,
                              hipStream_t stream) {
    const float* x    = (const float*)d_in[0];
    const float* W    = (const float*)d_in[1];
    const int*   erow = (const int*)d_in[2];
    const int*   ecol = (const int*)d_in[3];
    const float* eval = (const float*)d_in[4];
    float*       out  = (float*)d_out;

    // workspace layout (8B-aligned boundaries)
    const size_t H_ELEMS = (size_t)N_NODES * OUT_DIM;            // 12.8M
    unsigned short* hb    = (unsigned short*)d_ws;               // 25.6 MB
    int2*           gbuf  = (int2*)(hb + H_ELEMS);               // NBKT*CAP int2 (14.4 MB)
    unsigned int*   gcsr  = (unsigned int*)(gbuf + (size_t)NBKT * CAP);  // 7.2 MB
    int*            offs  = (int*)(gcsr + (size_t)NBKT * CAP);   // NBKT*BROWS ints
    int*            bend  = offs + NBKT * BROWS + 8;             // NBKT
    int*            bcnt  = bend + NBKT + 9;                     // NBKT*BSTR (padded)
    unsigned short* Wb    = (unsigned short*)(bcnt + NBKT * BSTR);  // 32768 bf16
    const size_t need = ((char*)(Wb + OUT_DIM * IN_DIM)) - (char*)d_ws;  // ~47.9 MB

    if (ws_size >= need) {
        w_to_bf16<<<(OUT_DIM * IN_DIM + 255) / 256, 256, 0, stream>>>(W, Wb, bcnt);
        bin_pass<<<NBLK, 256, 0, stream>>>(erow, ecol, eval, bcnt, gbuf);
        gemm_mfma<<<NGBLK, 512, 0, stream>>>(x, Wb, hb);
        sort_bucket<<<NBKT, 512, 0, stream>>>(gbuf, bcnt, gcsr, offs, bend);
        spmm_gather<<<N_NODES / 16, 256, 0, stream>>>(hb, offs, bend, gcsr, out);
    } else {
        gemm_plain<<<(N_NODES + 2 * BMT - 1) / (2 * BMT), 512, 0, stream>>>(x, W, hb);
        hipMemsetAsync(d_out, 0, (size_t)out_size * sizeof(float), stream);
        spmm_scatter<<<8192, 256, 0, stream>>>(hb, erow, ecol, eval, out);
    }
}

// Round 27
// 109.944 us; speedup vs baseline: 1.3201x; 1.3201x over previous
//
#include <hip/hip_runtime.h>
#include <hip/hip_fp16.h>

#define N_NODES 100000
#define N_EDGES 1600000
#define IN_DIM  256
#define OUT_DIM 128

#define BROWS  256                     // rows per bucket
#define NBKT   391                     // ceil(100000/256)
#define CAP    4608                    // per-bucket capacity (mean 4096 + 8 sigma)
#define CHUNK  8192                    // edges per bin block
#define NBLK   196                     // ceil(1600000/8192)
#define EPB    16                      // edges per thread in bin role (CHUNK/512)
#define DCAP   6144                    // LDS sort capacity
#define BSTR   16                      // bcnt stride (ints): 1 counter per 64B line

#define BMT    32                      // pipelined gemm tile rows (16 KB bf16 LDS)
#define NTILE  (N_NODES / BMT)         // 3125 (exact)
#define TPB    4                       // tiles per gemm block
#define NGBLK  ((NTILE + TPB - 1) / TPB)   // 782
#define BUFSZ  (BMT * 512)

typedef __attribute__((ext_vector_type(8))) short short8;
typedef __attribute__((ext_vector_type(4))) float f32x4;
typedef __attribute__((ext_vector_type(2))) float f32x2;

// f32 -> bf16 round-to-nearest-even (bit trick)
__device__ __forceinline__ unsigned short f2bf(float f) {
    unsigned int u = __float_as_uint(f);
    u += 0x7FFFu + ((u >> 16) & 1u);
    return (unsigned short)(u >> 16);
}
__device__ __forceinline__ float bf2f(unsigned int u16) {
    return __uint_as_float(u16 << 16);
}

__device__ __forceinline__ short8 pack8(float4 a, float4 b) {
    short8 s;
    s[0] = (short)f2bf(a.x); s[1] = (short)f2bf(a.y);
    s[2] = (short)f2bf(a.z); s[3] = (short)f2bf(a.w);
    s[4] = (short)f2bf(b.x); s[5] = (short)f2bf(b.y);
    s[6] = (short)f2bf(b.z); s[7] = (short)f2bf(b.w);
    return s;
}

// ---------------------------------------------------------------------------
// W (f32 [128][256]) -> bf16, once; block 0 also zeros padded bcnt.
// ---------------------------------------------------------------------------
__global__ __launch_bounds__(256) void w_to_bf16(const float* __restrict__ W,
                                                 unsigned short* __restrict__ Wb,
                                                 int* __restrict__ bcnt) {
    int i = blockIdx.x * 256 + threadIdx.x;
    if (i < OUT_DIM * IN_DIM) Wb[i] = f2bf(W[i]);
    if (blockIdx.x == 0) {
        for (int b = threadIdx.x; b < NBKT * BSTR; b += 256) bcnt[b] = 0;
    }
}

// ---------------------------------------------------------------------------
// Fused kernel (R24 config): blocks [0,NBLK) = bin pass with edge data
// CACHED IN REGISTERS (pass 1 loads once; pass 3 is pure LDS-atomic+store,
// no global reloads). Blocks [NBLK,+NGBLK) = 4-tile pipelined MFMA GEMM.
// ---------------------------------------------------------------------------
__global__ __launch_bounds__(512) void gemm_bin(const float* __restrict__ x,
                                                const unsigned short* __restrict__ Wb,
                                                unsigned short* __restrict__ hb,
                                                const int* __restrict__ erow,
                                                const int* __restrict__ ecol,
                                                const float* __restrict__ eval,
                                                int* __restrict__ bcnt,
                                                int2* __restrict__ gbuf) {
    __shared__ unsigned short xs[2 * BMT * 256];   // 32 KB
    const int tid = threadIdx.x;

    if (blockIdx.x < NBLK) {
        // ------------------ bin role (register-cached edges) ------------------
        int* h    = (int*)xs;
        int* gpos = h + NBKT;
        int* rcur = gpos + NBKT;
        for (int i = tid; i < NBKT; i += 512) { h[i] = 0; rcur[i] = 0; }
        __syncthreads();
        const int e0 = blockIdx.x * CHUNK;

        int          myrow[EPB];
        unsigned int myrec[EPB];
#pragma unroll
        for (int k = 0; k < EPB; ++k) {
            const int e  = e0 + k * 512 + tid;
            const bool ok = (e < N_EDGES);
            const int  ei = ok ? e : 0;
            int   r = erow[ei];
            int   c = ecol[ei];
            float v = eval[ei];
            myrow[k] = ok ? r : -1;
            unsigned int vb = __half_as_ushort(__float2half(v));
            myrec[k] = (vb << 17) | (unsigned int)c;
            if (ok) atomicAdd(&h[r >> 8], 1);
        }
        __syncthreads();
        for (int i = tid; i < NBKT; i += 512)
            gpos[i] = h[i] ? (i * CAP + atomicAdd(&bcnt[i * BSTR], h[i])) : 0;
        __syncthreads();
#pragma unroll
        for (int k = 0; k < EPB; ++k) {
            if (myrow[k] >= 0) {
                int b = myrow[k] >> 8;
                int pos = gpos[b] + atomicAdd(&rcur[b], 1);
                gbuf[pos] = make_int2((int)myrec[k], myrow[k]);
            }
        }
        return;
    }

    // ------------------ gemm role: 4-tile pipelined (R24-proven) ------------------
    const int g    = blockIdx.x - NBLK;
    const int t0   = g * TPB;
    const int wid  = tid >> 6;
    const int lane = tid & 63;
    const int l15  = lane & 15;
    const int g8   = (lane >> 4) * 8;
    const int col  = wid * 16 + l15;
    const int sw   = (l15 & 7) << 4;
    char* lb = (char*)xs;

    const int srow = tid >> 4;
    const int ca   = (tid & 15) * 8;
    const int swr  = (srow & 7) << 4;
    const int wbA  = (srow * 512 + ca * 2) ^ swr;
    const int wbB  = (srow * 512 + (ca + 128) * 2) ^ swr;

    short8 bfr[8];
    const unsigned short* wrow = Wb + (size_t)col * IN_DIM + g8;
#pragma unroll
    for (int kk = 0; kk < 8; ++kk)
        bfr[kk] = *(const short8*)(wrow + kk * 32);

    // prologue: load + write tile t0 into buffer 0
    {
        const int ti = t0;
        const int gr = (ti < NTILE) ? (ti * BMT + srow) : srow;
        const float4* sA = (const float4*)(x + (size_t)gr * IN_DIM + ca);
        const float4* sB = (const float4*)(x + (size_t)gr * IN_DIM + ca + 128);
        float4 f0 = sA[0], f1 = sA[1], f2 = sB[0], f3 = sB[1];
        *(short8*)(lb + wbA) = pack8(f0, f1);
        *(short8*)(lb + wbB) = pack8(f2, f3);
    }

#pragma unroll
    for (int i = 0; i < TPB; ++i) {
        float4 q0, q1, q2, q3;
        if (i + 1 < TPB) {
            const int ti = t0 + i + 1;
            const int gr = (ti < NTILE) ? (ti * BMT + srow) : srow;
            const float4* sA = (const float4*)(x + (size_t)gr * IN_DIM + ca);
            const float4* sB = (const float4*)(x + (size_t)gr * IN_DIM + ca + 128);
            q0 = sA[0]; q1 = sA[1]; q2 = sB[0]; q3 = sB[1];
        }
        __syncthreads();

        const int ti = t0 + i;
        const char* cb = lb + (i & 1) * BUFSZ;
        short8 a0[8], a1[8];
#pragma unroll
        for (int kk = 0; kk < 8; ++kk) {
            a0[kk] = *(const short8*)(cb + ((l15 * 512 + (kk * 32 + g8) * 2) ^ sw));
            a1[kk] = *(const short8*)(cb + (((l15 + 16) * 512 + (kk * 32 + g8) * 2) ^ sw));
        }
        f32x4 acc0 = {0.f, 0.f, 0.f, 0.f}, acc1 = {0.f, 0.f, 0.f, 0.f};
#pragma unroll
        for (int kk = 0; kk < 8; ++kk) {
            acc0 = __builtin_amdgcn_mfma_f32_16x16x32_bf16(a0[kk], bfr[kk], acc0, 0, 0, 0);
            acc1 = __builtin_amdgcn_mfma_f32_16x16x32_bf16(a1[kk], bfr[kk], acc1, 0, 0, 0);
        }
        if (ti < NTILE) {
            const int rb0 = ti * BMT + (lane >> 4) * 4;
            const int rb1 = rb0 + 16;
#pragma unroll
            for (int q = 0; q < 4; ++q) {
                hb[(size_t)(rb0 + q) * OUT_DIM + col] = f2bf(acc0[q]);
                hb[(size_t)(rb1 + q) * OUT_DIM + col] = f2bf(acc1[q]);
            }
        }
        if (i + 1 < TPB) {
            char* wbuf = lb + ((i + 1) & 1) * BUFSZ;
            *(short8*)(wbuf + wbA) = pack8(q0, q1);
            *(short8*)(wbuf + wbB) = pack8(q2, q3);
        }
    }
}

// ---------------------------------------------------------------------------
// Per-bucket LDS counting sort, 512 threads (R24-proven); cnt from padded bcnt.
// ---------------------------------------------------------------------------
__global__ __launch_bounds__(512) void sort_bucket(const int2* __restrict__ gbuf,
                                                   const int* __restrict__ bcnt,
                                                   unsigned int* __restrict__ gcsr,
                                                   int* __restrict__ offs,
                                                   int* __restrict__ bend) {
    __shared__ int rh[BROWS], rc[BROWS], tmp[256];
    __shared__ unsigned int lout[DCAP];
    const int b    = blockIdx.x;
    const int base = b * CAP;
    const int cnt  = bcnt[b * BSTR];
    const int r0   = b * BROWS;
    const int t    = threadIdx.x;

    if (t < BROWS) rh[t] = 0;
    __syncthreads();
    for (int i = t; i < cnt; i += 512)
        atomicAdd(&rh[gbuf[base + i].y - r0], 1);
    __syncthreads();

    int v = (t < 256) ? rh[t] : 0;
    if (t < 256) tmp[t] = v;
    __syncthreads();
    for (int d = 1; d < 256; d <<= 1) {
        int a = (t < 256 && t >= d) ? tmp[t - d] : 0;
        __syncthreads();
        if (t < 256) tmp[t] += a;
        __syncthreads();
    }
    if (t < 256) {
        int ex = tmp[t] - v;
        rc[t] = ex;
        offs[r0 + t] = base + ex;
    }
    if (t == 0) bend[b] = base + cnt;
    __syncthreads();

    if (cnt <= DCAP) {
        for (int i = t; i < cnt; i += 512) {
            int2 rr = gbuf[base + i];
            int p = atomicAdd(&rc[rr.y - r0], 1);
            lout[p] = (unsigned int)rr.x;
        }
        __syncthreads();
        for (int i = t; i < cnt; i += 512)
            gcsr[base + i] = lout[i];
    } else {  // unreachable (cnt <= CAP < DCAP); correctness fallback
        for (int i = t; i < cnt; i += 512) {
            int2 rr = gbuf[base + i];
            int p = atomicAdd(&rc[rr.y - r0], 1);
            gcsr[base + p] = (unsigned int)rr.x;
        }
    }
}

// ---------------------------------------------------------------------------
// Gather (R22-proven): 4 rows per wave, 8 channels/lane via uint4 loads.
// ---------------------------------------------------------------------------
__global__ __launch_bounds__(256) void spmm_gather(const unsigned short* __restrict__ hb,
                                                   const int* __restrict__ offs,
                                                   const int* __restrict__ bend,
                                                   const unsigned int* __restrict__ ccv,
                                                   float* __restrict__ out) {
    const int lane = threadIdx.x & 63;
    const int qtr  = lane >> 4;
    const int li   = lane & 15;
    const int r    = blockIdx.x * 16 + (threadIdx.x >> 6) * 4 + qtr;

    const int js = offs[r];
    const int je = ((r & (BROWS - 1)) == (BROWS - 1)) ? bend[r >> 8] : offs[r + 1];

    f32x2 acc0 = {0.f, 0.f}, acc1 = {0.f, 0.f};
    f32x2 acc2 = {0.f, 0.f}, acc3 = {0.f, 0.f};
    for (int j = js; __any(j < je); j += 8) {
        unsigned int e[8];
        uint4 p[8];
#pragma unroll
        for (int q = 0; q < 8; ++q) {
            int jj = j + q;
            e[q] = ccv[jj < je ? jj : 0];
        }
#pragma unroll
        for (int q = 0; q < 8; ++q)
            p[q] = *(const uint4*)(hb + (size_t)(e[q] & 0x1FFFFu) * OUT_DIM + li * 8);
#pragma unroll
        for (int q = 0; q < 8; ++q) {
            float v = (j + q < je)
                    ? __half2float(__ushort_as_half((unsigned short)(e[q] >> 17)))
                    : 0.f;
            f32x2 vv = {v, v};
            f32x2 h01 = { __uint_as_float(p[q].x << 16), __uint_as_float(p[q].x & 0xFFFF0000u) };
            f32x2 h23 = { __uint_as_float(p[q].y << 16), __uint_as_float(p[q].y & 0xFFFF0000u) };
            f32x2 h45 = { __uint_as_float(p[q].z << 16), __uint_as_float(p[q].z & 0xFFFF0000u) };
            f32x2 h67 = { __uint_as_float(p[q].w << 16), __uint_as_float(p[q].w & 0xFFFF0000u) };
            acc0 = __builtin_elementwise_fma(vv, h01, acc0);
            acc1 = __builtin_elementwise_fma(vv, h23, acc1);
            acc2 = __builtin_elementwise_fma(vv, h45, acc2);
            acc3 = __builtin_elementwise_fma(vv, h67, acc3);
        }
    }
    float4 o0 = {acc0.x, acc0.y, acc1.x, acc1.y};
    float4 o1 = {acc2.x, acc2.y, acc3.x, acc3.y};
    float* dst = out + (size_t)r * OUT_DIM + li * 8;
    *(float4*)dst       = o0;
    *(float4*)(dst + 4) = o1;
}

// ---------------------------------------------------------------------------
// Fallback path (workspace too small): plain gemm + atomic scatter.
// ---------------------------------------------------------------------------
__global__ __launch_bounds__(512) void gemm_plain(const float* __restrict__ x,
                                                  const float* __restrict__ W,
                                                  unsigned short* __restrict__ hb) {
    __shared__ unsigned short xs[2 * BMT * 256];
    const int tid = threadIdx.x;
    const int m0  = blockIdx.x * (2 * BMT);
    char* lb = (char*)xs;
    {
        const int row = tid >> 3;
        const int cs  = (tid & 7) * 32;
        const int gr  = m0 + row;
        if (gr < N_NODES) {
            const float4* src = (const float4*)(x + (size_t)gr * IN_DIM + cs);
#pragma unroll
            for (int i = 0; i < 4; ++i) {
                float4 a = src[2 * i], b = src[2 * i + 1];
                int byt = (row * 512 + (cs + 8 * i) * 2) ^ ((row & 7) << 4);
                *(short8*)(lb + byt) = pack8(a, b);
            }
        } else {
            short8 z = {0, 0, 0, 0, 0, 0, 0, 0};
#pragma unroll
            for (int i = 0; i < 4; ++i) {
                int byt = (row * 512 + (cs + 8 * i) * 2) ^ ((row & 7) << 4);
                *(short8*)(lb + byt) = z;
            }
        }
    }
    __syncthreads();
    const int wid  = tid >> 6;
    const int lane = tid & 63;
    const int l15  = lane & 15;
    const int g8   = (lane >> 4) * 8;
    short8 bfr[8];
    const float* wrowf = W + (size_t)(wid * 16 + l15) * IN_DIM + g8;
#pragma unroll
    for (int kk = 0; kk < 8; ++kk) {
        float4 wa = *(const float4*)(wrowf + kk * 32);
        float4 wb = *(const float4*)(wrowf + kk * 32 + 4);
        bfr[kk] = pack8(wa, wb);
    }
    const int col = wid * 16 + l15;
    const int sw  = (l15 & 7) << 4;
    const char* lbc = (const char*)xs;
#pragma unroll
    for (int rp = 0; rp < 2; ++rp) {
        const int r0 = rp * 32 + l15;
        const int r1 = r0 + 16;
        short8 a0[8], a1[8];
#pragma unroll
        for (int kk = 0; kk < 8; ++kk) {
            a0[kk] = *(const short8*)(lbc + ((r0 * 512 + (kk * 32 + g8) * 2) ^ sw));
            a1[kk] = *(const short8*)(lbc + ((r1 * 512 + (kk * 32 + g8) * 2) ^ sw));
        }
        f32x4 acc0 = {0.f, 0.f, 0.f, 0.f}, acc1 = {0.f, 0.f, 0.f, 0.f};
#pragma unroll
        for (int kk = 0; kk < 8; ++kk) {
            acc0 = __builtin_amdgcn_mfma_f32_16x16x32_bf16(a0[kk], bfr[kk], acc0, 0, 0, 0);
            acc1 = __builtin_amdgcn_mfma_f32_16x16x32_bf16(a1[kk], bfr[kk], acc1, 0, 0, 0);
        }
        const int rb0 = m0 + rp * 32 + (lane >> 4) * 4;
        const int rb1 = rb0 + 16;
#pragma unroll
        for (int i = 0; i < 4; ++i) {
            if (rb0 + i < N_NODES) hb[(size_t)(rb0 + i) * OUT_DIM + col] = f2bf(acc0[i]);
            if (rb1 + i < N_NODES) hb[(size_t)(rb1 + i) * OUT_DIM + col] = f2bf(acc1[i]);
        }
    }
}

__global__ __launch_bounds__(256) void spmm_scatter(const unsigned short* __restrict__ hb,
                                                    const int* __restrict__ erow,
                                                    const int* __restrict__ ecol,
                                                    const float* __restrict__ eval,
                                                    float* __restrict__ out) {
    const int lane = threadIdx.x & 63;
    const int eloc = threadIdx.x >> 6;
    const int stride = gridDim.x * 4;
    for (int e = blockIdx.x * 4 + eloc; e < N_EDGES; e += stride) {
        const int r = erow[e];
        const int c = ecol[e];
        const float v = eval[e];
        unsigned int p = *(const unsigned int*)(hb + (size_t)c * OUT_DIM + lane * 2);
        float* o = out + (size_t)r * OUT_DIM + lane * 2;
        unsafeAtomicAdd(o + 0, v * bf2f(p & 0xFFFFu));
        unsafeAtomicAdd(o + 1, v * bf2f(p >> 16));
    }
}

extern "C" void kernel_launch(void* const* d_in, const int* in_sizes, int n_in,
                              void* d_out, int out_size, void* d_ws, size_t ws_size,
                              hipStream_t stream) {
    const float* x    = (const float*)d_in[0];
    const float* W    = (const float*)d_in[1];
    const int*   erow = (const int*)d_in[2];
    const int*   ecol = (const int*)d_in[3];
    const float* eval = (const float*)d_in[4];
    float*       out  = (float*)d_out;

    // workspace layout (8B-aligned boundaries)
    const size_t H_ELEMS = (size_t)N_NODES * OUT_DIM;            // 12.8M
    unsigned short* hb    = (unsigned short*)d_ws;               // 25.6 MB
    int2*           gbuf  = (int2*)(hb + H_ELEMS);               // NBKT*CAP int2 (14.4 MB)
    unsigned int*   gcsr  = (unsigned int*)(gbuf + (size_t)NBKT * CAP);  // 7.2 MB
    int*            offs  = (int*)(gcsr + (size_t)NBKT * CAP);   // NBKT*BROWS ints
    int*            bend  = offs + NBKT * BROWS + 8;             // NBKT
    int*            bcnt  = bend + NBKT + 9;                     // NBKT*BSTR (padded)
    unsigned short* Wb    = (unsigned short*)(bcnt + NBKT * BSTR);  // 32768 bf16
    const size_t need = ((char*)(Wb + OUT_DIM * IN_DIM)) - (char*)d_ws;  // ~47.9 MB

    if (ws_size >= need) {
        w_to_bf16<<<(OUT_DIM * IN_DIM + 255) / 256, 256, 0, stream>>>(W, Wb, bcnt);
        gemm_bin<<<NBLK + NGBLK, 512, 0, stream>>>(x, Wb, hb, erow, ecol, eval, bcnt, gbuf);
        sort_bucket<<<NBKT, 512, 0, stream>>>(gbuf, bcnt, gcsr, offs, bend);
        spmm_gather<<<N_NODES / 16, 256, 0, stream>>>(hb, offs, bend, gcsr, out);
    } else {
        gemm_plain<<<(N_NODES + 2 * BMT - 1) / (2 * BMT), 512, 0, stream>>>(x, W, hb);
        hipMemsetAsync(d_out, 0, (size_t)out_size * sizeof(float), stream);
        spmm_scatter<<<8192, 256, 0, stream>>>(hb, erow, ecol, eval, out);
    }
}

// Round 28
// 108.514 us; speedup vs baseline: 1.3375x; 1.0132x over previous
//
#include <hip/hip_runtime.h>
#include <hip/hip_fp16.h>

#define N_NODES 100000
#define N_EDGES 1600000
#define IN_DIM  256
#define OUT_DIM 128

#define BROWS  256                     // rows per bucket
#define NBKT   391                     // ceil(100000/256)
#define CAP    4608                    // per-bucket capacity (mean 4096 + 8 sigma)
#define CHUNK  8192                    // edges per bin block
#define NBLK   196                     // ceil(1600000/8192)
#define EPB    16                      // edges per thread in bin role (CHUNK/512)
#define DCAP   6144                    // LDS sort capacity
#define BSTR   16                      // bcnt stride (ints): 1 counter per 64B line

#define BMT    32                      // pipelined gemm tile rows (16 KB bf16 LDS)
#define NTILE  (N_NODES / BMT)         // 3125 (exact)
#define TPB    4                       // tiles per gemm block
#define NGBLK  ((NTILE + TPB - 1) / TPB)   // 782
#define BUFSZ  (BMT * 512)

typedef __attribute__((ext_vector_type(8))) short short8;
typedef __attribute__((ext_vector_type(4))) float f32x4;
typedef __attribute__((ext_vector_type(2))) float f32x2;

// f32 -> bf16 round-to-nearest-even (bit trick)
__device__ __forceinline__ unsigned short f2bf(float f) {
    unsigned int u = __float_as_uint(f);
    u += 0x7FFFu + ((u >> 16) & 1u);
    return (unsigned short)(u >> 16);
}
__device__ __forceinline__ float bf2f(unsigned int u16) {
    return __uint_as_float(u16 << 16);
}

__device__ __forceinline__ short8 pack8(float4 a, float4 b) {
    short8 s;
    s[0] = (short)f2bf(a.x); s[1] = (short)f2bf(a.y);
    s[2] = (short)f2bf(a.z); s[3] = (short)f2bf(a.w);
    s[4] = (short)f2bf(b.x); s[5] = (short)f2bf(b.y);
    s[6] = (short)f2bf(b.z); s[7] = (short)f2bf(b.w);
    return s;
}

// ---------------------------------------------------------------------------
// W (f32 [128][256]) -> bf16, once; block 0 also zeros padded bcnt.
// ---------------------------------------------------------------------------
__global__ __launch_bounds__(256) void w_to_bf16(const float* __restrict__ W,
                                                 unsigned short* __restrict__ Wb,
                                                 int* __restrict__ bcnt) {
    int i = blockIdx.x * 256 + threadIdx.x;
    if (i < OUT_DIM * IN_DIM) Wb[i] = f2bf(W[i]);
    if (blockIdx.x == 0) {
        for (int b = threadIdx.x; b < NBKT * BSTR; b += 256) bcnt[b] = 0;
    }
}

// ---------------------------------------------------------------------------
// Fused kernel (R27-proven): blocks [0,NBLK) = bin pass with register-cached
// edges; blocks [NBLK,+NGBLK) = 4-tile pipelined MFMA GEMM.
// ---------------------------------------------------------------------------
__global__ __launch_bounds__(512) void gemm_bin(const float* __restrict__ x,
                                                const unsigned short* __restrict__ Wb,
                                                unsigned short* __restrict__ hb,
                                                const int* __restrict__ erow,
                                                const int* __restrict__ ecol,
                                                const float* __restrict__ eval,
                                                int* __restrict__ bcnt,
                                                int2* __restrict__ gbuf) {
    __shared__ unsigned short xs[2 * BMT * 256];   // 32 KB
    const int tid = threadIdx.x;

    if (blockIdx.x < NBLK) {
        // ------------------ bin role (register-cached edges) ------------------
        int* h    = (int*)xs;
        int* gpos = h + NBKT;
        int* rcur = gpos + NBKT;
        for (int i = tid; i < NBKT; i += 512) { h[i] = 0; rcur[i] = 0; }
        __syncthreads();
        const int e0 = blockIdx.x * CHUNK;

        int          myrow[EPB];
        unsigned int myrec[EPB];
#pragma unroll
        for (int k = 0; k < EPB; ++k) {
            const int e  = e0 + k * 512 + tid;
            const bool ok = (e < N_EDGES);
            const int  ei = ok ? e : 0;
            int   r = erow[ei];
            int   c = ecol[ei];
            float v = eval[ei];
            myrow[k] = ok ? r : -1;
            unsigned int vb = __half_as_ushort(__float2half(v));
            myrec[k] = (vb << 17) | (unsigned int)c;
            if (ok) atomicAdd(&h[r >> 8], 1);
        }
        __syncthreads();
        for (int i = tid; i < NBKT; i += 512)
            gpos[i] = h[i] ? (i * CAP + atomicAdd(&bcnt[i * BSTR], h[i])) : 0;
        __syncthreads();
#pragma unroll
        for (int k = 0; k < EPB; ++k) {
            if (myrow[k] >= 0) {
                int b = myrow[k] >> 8;
                int pos = gpos[b] + atomicAdd(&rcur[b], 1);
                gbuf[pos] = make_int2((int)myrec[k], myrow[k]);
            }
        }
        return;
    }

    // ------------------ gemm role: 4-tile pipelined (R24-proven) ------------------
    const int g    = blockIdx.x - NBLK;
    const int t0   = g * TPB;
    const int wid  = tid >> 6;
    const int lane = tid & 63;
    const int l15  = lane & 15;
    const int g8   = (lane >> 4) * 8;
    const int col  = wid * 16 + l15;
    const int sw   = (l15 & 7) << 4;
    char* lb = (char*)xs;

    const int srow = tid >> 4;
    const int ca   = (tid & 15) * 8;
    const int swr  = (srow & 7) << 4;
    const int wbA  = (srow * 512 + ca * 2) ^ swr;
    const int wbB  = (srow * 512 + (ca + 128) * 2) ^ swr;

    short8 bfr[8];
    const unsigned short* wrow = Wb + (size_t)col * IN_DIM + g8;
#pragma unroll
    for (int kk = 0; kk < 8; ++kk)
        bfr[kk] = *(const short8*)(wrow + kk * 32);

    // prologue: load + write tile t0 into buffer 0
    {
        const int ti = t0;
        const int gr = (ti < NTILE) ? (ti * BMT + srow) : srow;
        const float4* sA = (const float4*)(x + (size_t)gr * IN_DIM + ca);
        const float4* sB = (const float4*)(x + (size_t)gr * IN_DIM + ca + 128);
        float4 f0 = sA[0], f1 = sA[1], f2 = sB[0], f3 = sB[1];
        *(short8*)(lb + wbA) = pack8(f0, f1);
        *(short8*)(lb + wbB) = pack8(f2, f3);
    }

#pragma unroll
    for (int i = 0; i < TPB; ++i) {
        float4 q0, q1, q2, q3;
        if (i + 1 < TPB) {
            const int ti = t0 + i + 1;
            const int gr = (ti < NTILE) ? (ti * BMT + srow) : srow;
            const float4* sA = (const float4*)(x + (size_t)gr * IN_DIM + ca);
            const float4* sB = (const float4*)(x + (size_t)gr * IN_DIM + ca + 128);
            q0 = sA[0]; q1 = sA[1]; q2 = sB[0]; q3 = sB[1];
        }
        __syncthreads();

        const int ti = t0 + i;
        const char* cb = lb + (i & 1) * BUFSZ;
        short8 a0[8], a1[8];
#pragma unroll
        for (int kk = 0; kk < 8; ++kk) {
            a0[kk] = *(const short8*)(cb + ((l15 * 512 + (kk * 32 + g8) * 2) ^ sw));
            a1[kk] = *(const short8*)(cb + (((l15 + 16) * 512 + (kk * 32 + g8) * 2) ^ sw));
        }
        f32x4 acc0 = {0.f, 0.f, 0.f, 0.f}, acc1 = {0.f, 0.f, 0.f, 0.f};
#pragma unroll
        for (int kk = 0; kk < 8; ++kk) {
            acc0 = __builtin_amdgcn_mfma_f32_16x16x32_bf16(a0[kk], bfr[kk], acc0, 0, 0, 0);
            acc1 = __builtin_amdgcn_mfma_f32_16x16x32_bf16(a1[kk], bfr[kk], acc1, 0, 0, 0);
        }
        if (ti < NTILE) {
            const int rb0 = ti * BMT + (lane >> 4) * 4;
            const int rb1 = rb0 + 16;
#pragma unroll
            for (int q = 0; q < 4; ++q) {
                hb[(size_t)(rb0 + q) * OUT_DIM + col] = f2bf(acc0[q]);
                hb[(size_t)(rb1 + q) * OUT_DIM + col] = f2bf(acc1[q]);
            }
        }
        if (i + 1 < TPB) {
            char* wbuf = lb + ((i + 1) & 1) * BUFSZ;
            *(short8*)(wbuf + wbA) = pack8(q0, q1);
            *(short8*)(wbuf + wbB) = pack8(q2, q3);
        }
    }
}

// ---------------------------------------------------------------------------
// Per-bucket LDS counting sort, 512 threads (R24-proven); cnt from padded bcnt.
// ---------------------------------------------------------------------------
__global__ __launch_bounds__(512) void sort_bucket(const int2* __restrict__ gbuf,
                                                   const int* __restrict__ bcnt,
                                                   unsigned int* __restrict__ gcsr,
                                                   int* __restrict__ offs,
                                                   int* __restrict__ bend) {
    __shared__ int rh[BROWS], rc[BROWS], tmp[256];
    __shared__ unsigned int lout[DCAP];
    const int b    = blockIdx.x;
    const int base = b * CAP;
    const int cnt  = bcnt[b * BSTR];
    const int r0   = b * BROWS;
    const int t    = threadIdx.x;

    if (t < BROWS) rh[t] = 0;
    __syncthreads();
    for (int i = t; i < cnt; i += 512)
        atomicAdd(&rh[gbuf[base + i].y - r0], 1);
    __syncthreads();

    int v = (t < 256) ? rh[t] : 0;
    if (t < 256) tmp[t] = v;
    __syncthreads();
    for (int d = 1; d < 256; d <<= 1) {
        int a = (t < 256 && t >= d) ? tmp[t - d] : 0;
        __syncthreads();
        if (t < 256) tmp[t] += a;
        __syncthreads();
    }
    if (t < 256) {
        int ex = tmp[t] - v;
        rc[t] = ex;
        offs[r0 + t] = base + ex;
    }
    if (t == 0) bend[b] = base + cnt;
    __syncthreads();

    if (cnt <= DCAP) {
        for (int i = t; i < cnt; i += 512) {
            int2 rr = gbuf[base + i];
            int p = atomicAdd(&rc[rr.y - r0], 1);
            lout[p] = (unsigned int)rr.x;
        }
        __syncthreads();
        for (int i = t; i < cnt; i += 512)
            gcsr[base + i] = lout[i];
    } else {  // unreachable (cnt <= CAP < DCAP); correctness fallback
        for (int i = t; i < cnt; i += 512) {
            int2 rr = gbuf[base + i];
            int p = atomicAdd(&rc[rr.y - r0], 1);
            gcsr[base + p] = (unsigned int)rr.x;
        }
    }
}

// ---------------------------------------------------------------------------
// Gather: 4 rows per wave, 8 channels/lane via uint4 loads; 16-wide masked
// groups (one group covers the mean row) -> 2x in-flight bytes vs R27.
// ---------------------------------------------------------------------------
__global__ __launch_bounds__(256) void spmm_gather(const unsigned short* __restrict__ hb,
                                                   const int* __restrict__ offs,
                                                   const int* __restrict__ bend,
                                                   const unsigned int* __restrict__ ccv,
                                                   float* __restrict__ out) {
    const int lane = threadIdx.x & 63;
    const int qtr  = lane >> 4;
    const int li   = lane & 15;
    const int r    = blockIdx.x * 16 + (threadIdx.x >> 6) * 4 + qtr;

    const int js = offs[r];
    const int je = ((r & (BROWS - 1)) == (BROWS - 1)) ? bend[r >> 8] : offs[r + 1];

    f32x2 acc0 = {0.f, 0.f}, acc1 = {0.f, 0.f};
    f32x2 acc2 = {0.f, 0.f}, acc3 = {0.f, 0.f};
    for (int j = js; __any(j < je); j += 16) {
        unsigned int e[16];
        uint4 p[16];
#pragma unroll
        for (int q = 0; q < 16; ++q) {
            int jj = j + q;
            e[q] = ccv[jj < je ? jj : 0];
        }
#pragma unroll
        for (int q = 0; q < 16; ++q)
            p[q] = *(const uint4*)(hb + (size_t)(e[q] & 0x1FFFFu) * OUT_DIM + li * 8);
#pragma unroll
        for (int q = 0; q < 16; ++q) {
            float v = (j + q < je)
                    ? __half2float(__ushort_as_half((unsigned short)(e[q] >> 17)))
                    : 0.f;
            f32x2 vv = {v, v};
            f32x2 h01 = { __uint_as_float(p[q].x << 16), __uint_as_float(p[q].x & 0xFFFF0000u) };
            f32x2 h23 = { __uint_as_float(p[q].y << 16), __uint_as_float(p[q].y & 0xFFFF0000u) };
            f32x2 h45 = { __uint_as_float(p[q].z << 16), __uint_as_float(p[q].z & 0xFFFF0000u) };
            f32x2 h67 = { __uint_as_float(p[q].w << 16), __uint_as_float(p[q].w & 0xFFFF0000u) };
            acc0 = __builtin_elementwise_fma(vv, h01, acc0);
            acc1 = __builtin_elementwise_fma(vv, h23, acc1);
            acc2 = __builtin_elementwise_fma(vv, h45, acc2);
            acc3 = __builtin_elementwise_fma(vv, h67, acc3);
        }
    }
    float4 o0 = {acc0.x, acc0.y, acc1.x, acc1.y};
    float4 o1 = {acc2.x, acc2.y, acc3.x, acc3.y};
    float* dst = out + (size_t)r * OUT_DIM + li * 8;
    *(float4*)dst       = o0;
    *(float4*)(dst + 4) = o1;
}

// ---------------------------------------------------------------------------
// Fallback path (workspace too small): plain gemm + atomic scatter.
// ---------------------------------------------------------------------------
__global__ __launch_bounds__(512) void gemm_plain(const float* __restrict__ x,
                                                  const float* __restrict__ W,
                                                  unsigned short* __restrict__ hb) {
    __shared__ unsigned short xs[2 * BMT * 256];
    const int tid = threadIdx.x;
    const int m0  = blockIdx.x * (2 * BMT);
    char* lb = (char*)xs;
    {
        const int row = tid >> 3;
        const int cs  = (tid & 7) * 32;
        const int gr  = m0 + row;
        if (gr < N_NODES) {
            const float4* src = (const float4*)(x + (size_t)gr * IN_DIM + cs);
#pragma unroll
            for (int i = 0; i < 4; ++i) {
                float4 a = src[2 * i], b = src[2 * i + 1];
                int byt = (row * 512 + (cs + 8 * i) * 2) ^ ((row & 7) << 4);
                *(short8*)(lb + byt) = pack8(a, b);
            }
        } else {
            short8 z = {0, 0, 0, 0, 0, 0, 0, 0};
#pragma unroll
            for (int i = 0; i < 4; ++i) {
                int byt = (row * 512 + (cs + 8 * i) * 2) ^ ((row & 7) << 4);
                *(short8*)(lb + byt) = z;
            }
        }
    }
    __syncthreads();
    const int wid  = tid >> 6;
    const int lane = tid & 63;
    const int l15  = lane & 15;
    const int g8   = (lane >> 4) * 8;
    short8 bfr[8];
    const float* wrowf = W + (size_t)(wid * 16 + l15) * IN_DIM + g8;
#pragma unroll
    for (int kk = 0; kk < 8; ++kk) {
        float4 wa = *(const float4*)(wrowf + kk * 32);
        float4 wb = *(const float4*)(wrowf + kk * 32 + 4);
        bfr[kk] = pack8(wa, wb);
    }
    const int col = wid * 16 + l15;
    const int sw  = (l15 & 7) << 4;
    const char* lbc = (const char*)xs;
#pragma unroll
    for (int rp = 0; rp < 2; ++rp) {
        const int r0 = rp * 32 + l15;
        const int r1 = r0 + 16;
        short8 a0[8], a1[8];
#pragma unroll
        for (int kk = 0; kk < 8; ++kk) {
            a0[kk] = *(const short8*)(lbc + ((r0 * 512 + (kk * 32 + g8) * 2) ^ sw));
            a1[kk] = *(const short8*)(lbc + ((r1 * 512 + (kk * 32 + g8) * 2) ^ sw));
        }
        f32x4 acc0 = {0.f, 0.f, 0.f, 0.f}, acc1 = {0.f, 0.f, 0.f, 0.f};
#pragma unroll
        for (int kk = 0; kk < 8; ++kk) {
            acc0 = __builtin_amdgcn_mfma_f32_16x16x32_bf16(a0[kk], bfr[kk], acc0, 0, 0, 0);
            acc1 = __builtin_amdgcn_mfma_f32_16x16x32_bf16(a1[kk], bfr[kk], acc1, 0, 0, 0);
        }
        const int rb0 = m0 + rp * 32 + (lane >> 4) * 4;
        const int rb1 = rb0 + 16;
#pragma unroll
        for (int i = 0; i < 4; ++i) {
            if (rb0 + i < N_NODES) hb[(size_t)(rb0 + i) * OUT_DIM + col] = f2bf(acc0[i]);
            if (rb1 + i < N_NODES) hb[(size_t)(rb1 + i) * OUT_DIM + col] = f2bf(acc1[i]);
        }
    }
}

__global__ __launch_bounds__(256) void spmm_scatter(const unsigned short* __restrict__ hb,
                                                    const int* __restrict__ erow,
                                                    const int* __restrict__ ecol,
                                                    const float* __restrict__ eval,
                                                    float* __restrict__ out) {
    const int lane = threadIdx.x & 63;
    const int eloc = threadIdx.x >> 6;
    const int stride = gridDim.x * 4;
    for (int e = blockIdx.x * 4 + eloc; e < N_EDGES; e += stride) {
        const int r = erow[e];
        const int c = ecol[e];
        const float v = eval[e];
        unsigned int p = *(const unsigned int*)(hb + (size_t)c * OUT_DIM + lane * 2);
        float* o = out + (size_t)r * OUT_DIM + lane * 2;
        unsafeAtomicAdd(o + 0, v * bf2f(p & 0xFFFFu));
        unsafeAtomicAdd(o + 1, v * bf2f(p >> 16));
    }
}

extern "C" void kernel_launch(void* const* d_in, const int* in_sizes, int n_in,
                              void* d_out, int out_size, void* d_ws, size_t ws_size,
                              hipStream_t stream) {
    const float* x    = (const float*)d_in[0];
    const float* W    = (const float*)d_in[1];
    const int*   erow = (const int*)d_in[2];
    const int*   ecol = (const int*)d_in[3];
    const float* eval = (const float*)d_in[4];
    float*       out  = (float*)d_out;

    // workspace layout (8B-aligned boundaries)
    const size_t H_ELEMS = (size_t)N_NODES * OUT_DIM;            // 12.8M
    unsigned short* hb    = (unsigned short*)d_ws;               // 25.6 MB
    int2*           gbuf  = (int2*)(hb + H_ELEMS);               // NBKT*CAP int2 (14.4 MB)
    unsigned int*   gcsr  = (unsigned int*)(gbuf + (size_t)NBKT * CAP);  // 7.2 MB
    int*            offs  = (int*)(gcsr + (size_t)NBKT * CAP);   // NBKT*BROWS ints
    int*            bend  = offs + NBKT * BROWS + 8;             // NBKT
    int*            bcnt  = bend + NBKT + 9;                     // NBKT*BSTR (padded)
    unsigned short* Wb    = (unsigned short*)(bcnt + NBKT * BSTR);  // 32768 bf16
    const size_t need = ((char*)(Wb + OUT_DIM * IN_DIM)) - (char*)d_ws;  // ~47.9 MB

    if (ws_size >= need) {
        w_to_bf16<<<(OUT_DIM * IN_DIM + 255) / 256, 256, 0, stream>>>(W, Wb, bcnt);
        gemm_bin<<<NBLK + NGBLK, 512, 0, stream>>>(x, Wb, hb, erow, ecol, eval, bcnt, gbuf);
        sort_bucket<<<NBKT, 512, 0, stream>>>(gbuf, bcnt, gcsr, offs, bend);
        spmm_gather<<<N_NODES / 16, 256, 0, stream>>>(hb, offs, bend, gcsr, out);
    } else {
        gemm_plain<<<(N_NODES + 2 * BMT - 1) / (2 * BMT), 512, 0, stream>>>(x, W, hb);
        hipMemsetAsync(d_out, 0, (size_t)out_size * sizeof(float), stream);
        spmm_scatter<<<8192, 256, 0, stream>>>(hb, erow, ecol, eval, out);
    }
}